// Round 1
// baseline (137.205 us; speedup 1.0000x reference)
//
#include <hip/hip_runtime.h>
#include <cstdint>
#include <cstddef>

typedef unsigned short u16;
typedef unsigned int   u32;
typedef __attribute__((ext_vector_type(4))) float f32x4;
typedef __attribute__((ext_vector_type(8))) short bf16x8;
typedef __attribute__((ext_vector_type(4))) unsigned short u16x4;
typedef __attribute__((ext_vector_type(4))) u32 u32x4;

#define DEVI static __device__ __forceinline__
#define MFMA16(a,b,c) __builtin_amdgcn_mfma_f32_16x16x32_bf16((a),(b),(c),0,0,0)

// f32 -> bf16 bits, round-to-nearest-even
DEVI u16 f2b(float f) {
  u32 u = __builtin_bit_cast(u32, f);
  u32 r = u + 0x7fffu + ((u >> 16) & 1u);
  return (u16)(r >> 16);
}

DEVI void load_lds16(const void* g, void* l) {
  __builtin_amdgcn_global_load_lds(
      (const __attribute__((address_space(1))) u32*)g,
      (__attribute__((address_space(3))) u32*)l, 16, 0, 0);
}

DEVI int perm_o(int o) { return 4 * (o & 63) + (o >> 6); }   // o' = h*64+i -> o = 4i+h
DEVI int swzb(int byteoff, int row) { return byteoff ^ ((row & 7) << 4); }

// ---------------------------------------------------------------- weights prep
__global__ __launch_bounds__(256) void k_prep_w(
    const float* __restrict__ wq, const float* __restrict__ wk,
    const float* __restrict__ wv, const float* __restrict__ wm,
    const float* __restrict__ bq, const float* __restrict__ bk, const float* __restrict__ bv,
    u16* __restrict__ WQ, u16* __restrict__ WK, u16* __restrict__ WV, u16* __restrict__ WM,
    float* __restrict__ BQ, float* __restrict__ BK, float* __restrict__ BV)
{
  int row = blockIdx.x, t = threadIdx.x, m = blockIdx.y;
  if (m == 0)      WQ[row * 256 + t] = f2b(wq[perm_o(row) * 256 + t]);
  else if (m == 1) WK[row * 256 + t] = f2b(wk[perm_o(row) * 256 + t]);
  else if (m == 2) WV[row * 256 + t] = f2b(wv[perm_o(row) * 256 + t]);
  else if (m == 3) WM[row * 256 + t] = f2b(wm[row * 256 + perm_o(t)]);
  else if (row == 0) {
    BQ[t] = bq[perm_o(t)];
    BK[t] = bk[perm_o(t)];
    BV[t] = bv[perm_o(t)];
  }
}

// ---------------------------------------------- transpose+convert: [b][c][n]f32 -> [b][n][c]bf16
__global__ __launch_bounds__(256) void k_transpose(
    const float* __restrict__ q, const float* __restrict__ k, const float* __restrict__ v,
    u16* __restrict__ xq, u16* __restrict__ xk, u16* __restrict__ xv)
{
  __shared__ u16 tile[64][68];   // [c][n], padded
  const int N = 2048, D = 256;
  int n0 = blockIdx.x * 64, c0 = blockIdx.y * 64;
  int b = blockIdx.z & 7, which = blockIdx.z >> 3;
  const float* src = (which == 0 ? q : which == 1 ? k : v) + (size_t)b * D * N;
  u16* dst = (which == 0 ? xq : which == 1 ? xk : xv) + (size_t)b * N * D;
  int t = threadIdx.x;
  int cl = t >> 4, ng = t & 15;
#pragma unroll
  for (int cc = 0; cc < 4; ++cc) {
    int c = cl + 16 * cc;
    f32x4 val = *(const f32x4*)&src[(size_t)(c0 + c) * N + n0 + ng * 4];
#pragma unroll
    for (int j = 0; j < 4; ++j) tile[c][ng * 4 + j] = f2b(val[j]);
  }
  __syncthreads();
  int n = t & 63, cq = t >> 6;
  union { u16 s[16]; u32x4 v4[2]; } pk;
#pragma unroll
  for (int j = 0; j < 16; ++j) pk.s[j] = tile[cq * 16 + j][n];
  u32x4* o = (u32x4*)&dst[(size_t)(n0 + n) * D + c0 + cq * 16];
  o[0] = pk.v4[0];
  o[1] = pk.v4[1];
}

// ---------------------------------------------------------------- GEMM: C = A[M,256] * B[N',256]^T
// EPI 0: Q/K-proj  -> bf16 [b][h][n][i]   (rows = n, cols = o' = h*64+i), bias[col]
// EPI 1: V-proj    -> bf16 [b][row][col]  (rows = o', cols = n), bias[row]
// EPI 2: M-proj    -> f32  [b][row][col]  + bias[row]
template<int EPI>
__global__ __launch_bounds__(256) void k_gemm(
    const u16* __restrict__ A, long sA,
    const u16* __restrict__ Bm, long sB,
    const float* __restrict__ bias,
    void* __restrict__ out, long sOut)
{
  __shared__ u16 lA[128 * 64];
  __shared__ u16 lB[128 * 64];
  int t = threadIdx.x, b = blockIdx.z;
  const u16* Ab = A + (size_t)b * sA + (size_t)blockIdx.x * 128 * 256;
  const u16* Bb = Bm + (size_t)b * sB + (size_t)blockIdx.y * 128 * 256;
  int l = t & 63, w = t >> 6, g = l >> 4, col = l & 15;
  int wr = w >> 1, wc = w & 1;
  f32x4 acc[4][4] = {};
  for (int k0 = 0; k0 < 256; k0 += 64) {
    __syncthreads();
#pragma unroll
    for (int s = 0; s < 4; ++s) {
      int slot = t + 256 * s;
      int r = slot >> 3, ch = slot & 7;
      load_lds16(Ab + (size_t)r * 256 + k0 + ch * 8, (char*)lA + slot * 16);
      load_lds16(Bb + (size_t)r * 256 + k0 + ch * 8, (char*)lB + slot * 16);
    }
    asm volatile("s_waitcnt vmcnt(0)" ::: "memory");
    __syncthreads();
#pragma unroll
    for (int kc = 0; kc < 2; ++kc) {
      bf16x8 af[4], bfr[4];
#pragma unroll
      for (int mt = 0; mt < 4; ++mt)
        af[mt] = *(const bf16x8*)&lA[(wr * 64 + mt * 16 + col) * 64 + kc * 32 + g * 8];
#pragma unroll
      for (int nt = 0; nt < 4; ++nt)
        bfr[nt] = *(const bf16x8*)&lB[(wc * 64 + nt * 16 + col) * 64 + kc * 32 + g * 8];
#pragma unroll
      for (int mt = 0; mt < 4; ++mt)
#pragma unroll
        for (int nt = 0; nt < 4; ++nt)
          acc[mt][nt] = MFMA16(af[mt], bfr[nt], acc[mt][nt]);
    }
  }
  if (EPI == 0) {
    u16* o = (u16*)out + (size_t)b * sOut;
#pragma unroll
    for (int nt = 0; nt < 4; ++nt) {
      int op = blockIdx.y * 128 + wc * 64 + nt * 16 + col;
      int hh = op >> 6, ii = op & 63;
      float bv = bias[op];
#pragma unroll
      for (int mt = 0; mt < 4; ++mt) {
        int nbase = blockIdx.x * 128 + wr * 64 + mt * 16 + g * 4;
#pragma unroll
        for (int r = 0; r < 4; ++r)
          o[((size_t)(hh * 2048 + nbase + r)) * 64 + ii] = f2b(acc[mt][nt][r] + bv);
      }
    }
  } else if (EPI == 1) {
    u16* o = (u16*)out + (size_t)b * sOut;
#pragma unroll
    for (int mt = 0; mt < 4; ++mt)
#pragma unroll
      for (int r = 0; r < 4; ++r) {
        int row = blockIdx.x * 128 + wr * 64 + mt * 16 + g * 4 + r;
        float bv = bias[row];
#pragma unroll
        for (int nt = 0; nt < 4; ++nt) {
          int cn = blockIdx.y * 128 + wc * 64 + nt * 16 + col;
          o[(size_t)row * 2048 + cn] = f2b(acc[mt][nt][r] + bv);
        }
      }
  } else {
    float* o = (float*)out + (size_t)b * sOut;
#pragma unroll
    for (int mt = 0; mt < 4; ++mt)
#pragma unroll
      for (int r = 0; r < 4; ++r) {
        int row = blockIdx.x * 128 + wr * 64 + mt * 16 + g * 4 + r;
        float bv = bias[row];
#pragma unroll
        for (int nt = 0; nt < 4; ++nt) {
          int cn = blockIdx.y * 128 + wc * 64 + nt * 16 + col;
          o[(size_t)row * 2048 + cn] = acc[mt][nt][r] + bv;
        }
      }
  }
}

// ---------------------------------------------------------------- flash attention
// Qt,Kt: [b][h][n][64] bf16 ; Vw: [b][o'=h*64+i][n] bf16 ; Xws: [b][n][c'=h*64+i] bf16
__global__ __launch_bounds__(256) void k_attn(
    const u16* __restrict__ Qt, const u16* __restrict__ Kt,
    const u16* __restrict__ Vw, u16* __restrict__ Xws)
{
  __shared__ u16 lK[64 * 64];        // [m][i], XOR-swizzled content
  __shared__ u16 lV[64 * 64];        // [i][m], XOR-swizzled content
  __shared__ u16 lP[4][16 * 72];     // per-wave [n][m], padded to 72
  int t = threadIdx.x, l = t & 63, w = t >> 6, g = l >> 4, col = l & 15;
  int nb = blockIdx.x, hh = blockIdx.y, b = blockIdx.z;
  const u16* Qb = Qt + ((size_t)(b * 4 + hh) * 2048) * 64;
  const u16* Kb = Kt + ((size_t)(b * 4 + hh) * 2048) * 64;
  const u16* Vb = Vw + ((size_t)(b * 256 + hh * 64)) * 2048;
  int nq = nb * 64 + w * 16 + col;
  bf16x8 qf0 = *(const bf16x8*)&Qb[(size_t)nq * 64 + g * 8];
  bf16x8 qf1 = *(const bf16x8*)&Qb[(size_t)nq * 64 + 32 + g * 8];
  f32x4 xacc[4] = {};
  float m_run = -1e30f, l_run = 0.f;

  for (int m0 = 0; m0 < 2048; m0 += 64) {
    __syncthreads();
    const char* ktile = (const char*)(Kb + (size_t)m0 * 64);
#pragma unroll
    for (int ss = 0; ss < 2; ++ss) {
      int s = t + 256 * ss;
      int boff = (s * 16) ^ (((s >> 3) & 7) << 4);
      load_lds16(ktile + boff, (char*)lK + s * 16);
    }
#pragma unroll
    for (int ss = 0; ss < 2; ++ss) {
      int s = t + 256 * ss;
      int i = s >> 3, ch = s & 7;
      const char* vsrc = (const char*)(Vb + (size_t)i * 2048 + m0) + ((ch ^ (i & 7)) << 4);
      load_lds16(vsrc, (char*)lV + s * 16);
    }
    asm volatile("s_waitcnt vmcnt(0)" ::: "memory");
    __syncthreads();

    // S^T[m][n] = sum_i K[m][i] * Q[n][i]
    f32x4 sacc[4] = {};
#pragma unroll
    for (int kc = 0; kc < 2; ++kc) {
      bf16x8 qf = kc ? qf1 : qf0;
#pragma unroll
      for (int mt = 0; mt < 4; ++mt) {
        int row = mt * 16 + col;
        bf16x8 kf = *(const bf16x8*)((const char*)lK + swzb(row * 128 + kc * 64 + g * 16, row));
        sacc[mt] = MFMA16(kf, qf, sacc[mt]);
      }
    }
    // online softmax over m (rows); this lane's column n = col
    float pmax = -1e30f;
#pragma unroll
    for (int mt = 0; mt < 4; ++mt)
#pragma unroll
      for (int r = 0; r < 4; ++r) pmax = fmaxf(pmax, sacc[mt][r]);
    pmax = fmaxf(pmax, __shfl_xor(pmax, 16));
    pmax = fmaxf(pmax, __shfl_xor(pmax, 32));
    float mnew = fmaxf(m_run, pmax * 0.125f);
    float fscale = __expf(m_run - mnew);
    float psum = 0.f;
    u16* prow = &lP[w][col * 72];
#pragma unroll
    for (int mt = 0; mt < 4; ++mt) {
      u16x4 pv;
#pragma unroll
      for (int r = 0; r < 4; ++r) {
        float p = __expf(sacc[mt][r] * 0.125f - mnew);
        psum += p;
        pv[r] = f2b(p);
      }
      *(u16x4*)&prow[mt * 16 + g * 4] = pv;
    }
    psum += __shfl_xor(psum, 16);
    psum += __shfl_xor(psum, 32);
    l_run = l_run * fscale + psum;
    m_run = mnew;
#pragma unroll
    for (int it = 0; it < 4; ++it) xacc[it] *= fscale;
    asm volatile("s_waitcnt lgkmcnt(0)" ::: "memory");
    // x^T[i][n] += sum_m V^T[i][m] * P[n][m]
#pragma unroll
    for (int kc = 0; kc < 2; ++kc) {
      bf16x8 pf = *(const bf16x8*)&lP[w][col * 72 + kc * 32 + g * 8];
#pragma unroll
      for (int it = 0; it < 4; ++it) {
        int row = it * 16 + col;
        bf16x8 vf = *(const bf16x8*)((const char*)lV + swzb(row * 128 + kc * 64 + g * 16, row));
        xacc[it] = MFMA16(vf, pf, xacc[it]);
      }
    }
  }
  float inv = 1.0f / l_run;
  u16* Ob = Xws + (size_t)b * 2048 * 256;
#pragma unroll
  for (int it = 0; it < 4; ++it) {
    u16x4 vv;
#pragma unroll
    for (int r = 0; r < 4; ++r) vv[r] = f2b(xacc[it][r] * inv);
    *(u16x4*)&Ob[(size_t)nq * 256 + hh * 64 + it * 16 + g * 4] = vv;
  }
}

// ---------------------------------------------------------------- launch
extern "C" void kernel_launch(void* const* d_in, const int* in_sizes, int n_in,
                              void* d_out, int out_size, void* d_ws, size_t ws_size,
                              hipStream_t stream)
{
  const float* q_in = (const float*)d_in[0];
  const float* k_in = (const float*)d_in[1];
  const float* v_in = (const float*)d_in[2];
  const float* w_q  = (const float*)d_in[3];
  const float* b_q  = (const float*)d_in[4];
  const float* w_k  = (const float*)d_in[5];
  const float* b_k  = (const float*)d_in[6];
  const float* w_v  = (const float*)d_in[7];
  const float* b_v  = (const float*)d_in[8];
  const float* w_m  = (const float*)d_in[9];
  const float* b_m  = (const float*)d_in[10];

  char* ws = (char*)d_ws;
  u16* XT_Q = (u16*)(ws + 0);           // [8][2048][256] bf16; reused as XWS after Q-proj
  u16* XT_K = (u16*)(ws + 8388608);
  u16* XT_V = (u16*)(ws + 16777216);
  u16* QT   = (u16*)(ws + 25165824);    // [8][4][2048][64]
  u16* KT   = (u16*)(ws + 33554432);
  u16* VW   = (u16*)(ws + 41943040);    // [8][256][2048]
  u16* WQ   = (u16*)(ws + 50331648);
  u16* WK   = (u16*)(ws + 50462720);
  u16* WV   = (u16*)(ws + 50593792);
  u16* WM   = (u16*)(ws + 50724864);
  float* BQ = (float*)(ws + 50855936);
  float* BK = (float*)(ws + 50856960);
  float* BV = (float*)(ws + 50857984);

  k_prep_w<<<dim3(256, 5), 256, 0, stream>>>(w_q, w_k, w_v, w_m, b_q, b_k, b_v,
                                             WQ, WK, WV, WM, BQ, BK, BV);
  k_transpose<<<dim3(32, 4, 24), 256, 0, stream>>>(q_in, k_in, v_in, XT_Q, XT_K, XT_V);
  k_gemm<0><<<dim3(16, 2, 8), 256, 0, stream>>>(XT_Q, 2048L * 256, WQ, 0, BQ, QT, 4L * 2048 * 64);
  k_gemm<0><<<dim3(16, 2, 8), 256, 0, stream>>>(XT_K, 2048L * 256, WK, 0, BK, KT, 4L * 2048 * 64);
  k_gemm<1><<<dim3(2, 16, 8), 256, 0, stream>>>(WV, 0, XT_V, 2048L * 256, BV, VW, 256L * 2048);
  k_attn<<<dim3(32, 4, 8), 256, 0, stream>>>(QT, KT, VW, XT_Q);
  k_gemm<2><<<dim3(2, 16, 8), 256, 0, stream>>>(WM, 0, XT_Q, 2048L * 256, b_m, d_out, 256L * 2048);
}